// Round 21
// baseline (268.949 us; speedup 1.0000x reference)
//
#include <hip/hip_runtime.h>

// Problem constants
#define BATCH   4096
#define NF      39          // num_field
#define ED      16          // embedding size
#define IN_DIM  624         // NF*ED
#define DW      400
#define BN_EPS  1e-5f
#define AK1     640         // padded deep K for layer 1 input (624 -> 640)
#define NKS1    20          // AK1/32
#define NKS2    13          // 400 -> 416 padded
#define WCOL    416         // padded deep-weight column count
#define NK1     117         // CIN layer-1 k16 steps: 39 m * 48 h / 16 (h padded 39->48)
#define NK2     156         // CIN layer-2 k16 steps: 39 m * 64 h / 16

typedef __attribute__((ext_vector_type(8))) short short8;
typedef __attribute__((ext_vector_type(16))) float f32x16;
typedef __attribute__((ext_vector_type(4))) float f32x4;
typedef __attribute__((ext_vector_type(2))) float f32x2;
typedef unsigned short u16;

__device__ inline unsigned pack_hi2(float a, float b) {
  return __builtin_amdgcn_perm(__float_as_uint(b), __float_as_uint(a), 0x07060302u);
}
__device__ inline unsigned bf16_rne(float f) {
  unsigned u = __float_as_uint(f);
  u += 0x7fff + ((u >> 16) & 1);
  return u >> 16;
}
__device__ inline float bf2f(u16 v) { return __uint_as_float((unsigned)v << 16); }

#define CIN1_E (NK1 * 2048)          // 239616
#define CIN2_E (NK2 * 2048)          // 319488
#define D1_E  (NKS1 * WCOL * 32)     // 266240
#define D2_E  (NKS2 * WCOL * 32)     // 173056
#define PREP_E (CIN1_E + CIN2_E + D1_E + D2_E + 1600)
#define PREP_B ((PREP_E + 255) / 256)
#define GATH_B (BATCH / 4)

// ---------------------------------------------------------------------------
// Merged: blocks < GATH_B gather embeddings (wave per sample, no barriers);
// rest pack weights into B-fragment layout and zero BN-stat accumulators.
// CIN pack layout (32x32x16): wp[k16][col 128][kk 16]; lane reads 8 bf16 at
// col*16 + khalf*8.
//   layer1: k = m*48 + h  (h<48, zero for h>=39)  -> k16 = m*3 + s, h=s*16+kk
//   layer2: k = m*64 + h  (h<64)                  -> k16 = m*4 + s
// ---------------------------------------------------------------------------
__global__ __launch_bounds__(256) void k_gp(const int* __restrict__ idx,
    const float* __restrict__ emb, const float* __restrict__ lw,
    const float* __restrict__ lb, const float* __restrict__ w1,
    const float* __restrict__ w2, const float* __restrict__ dw1,
    const float* __restrict__ dw2, u16* __restrict__ flatb,
    float* __restrict__ lp, u16* __restrict__ wp1, u16* __restrict__ wp2,
    u16* __restrict__ wpd1, u16* __restrict__ wpd2, float* __restrict__ gstat) {
  int t = threadIdx.x;
  if (blockIdx.x < GATH_B) {
    int lane = t & 63;
    int b = blockIdx.x * 4 + (t >> 6);
    int sj = (lane < NF) ? idx[b * NF + lane] : 0;
    float acc = 0.f;
#pragma unroll
    for (int i = 0; i < 10; i++) {
      int e = lane + i * 64;
      if (e < IN_DIM) {
        int f = e >> 4;
        int row = __shfl(sj, f);
        float v = emb[(size_t)row * ED + (e & 15)];
        flatb[(size_t)b * AK1 + e] = (u16)bf16_rne(v);
        acc = fmaf(v, lw[e], acc);
      } else {
        flatb[(size_t)b * AK1 + e] = 0;
      }
    }
#pragma unroll
    for (int k = 1; k < 64; k <<= 1) acc += __shfl_xor(acc, k);
    if (lane == 0) lp[b] = acc + lb[0];
  } else {
    int e = (blockIdx.x - GATH_B) * 256 + t;
    if (e < CIN1_E) {
      int k16 = e >> 11, r = e & 2047, col = r >> 4, kk = r & 15;
      int mg = k16 / 3, sg = k16 - mg * 3;      // m = mg, h = sg*16+kk
      int h = sg * 16 + kk;
      wp1[e] = (h < NF) ? (u16)bf16_rne(w1[(size_t)col * (NF * NF) + h * NF + mg])
                        : (u16)0;
    } else if (e < CIN1_E + CIN2_E) {
      int e2 = e - CIN1_E;
      int k16 = e2 >> 11, r = e2 & 2047, col = r >> 4, kk = r & 15;
      int k = k16 * 16 + kk, h = k & 63, m = k >> 6;
      wp2[e2] = (u16)bf16_rne(w2[(size_t)col * (64 * NF) + h * NF + m]);
    } else if (e < CIN1_E + CIN2_E + D1_E) {
      int e2 = e - CIN1_E - CIN2_E;
      int ksg = e2 / (WCOL * 32), r = e2 - ksg * (WCOL * 32);
      int col = r >> 5, kk = r & 31;
      int k = ksg * 32 + kk;
      wpd1[e2] = (k < IN_DIM && col < DW) ? (u16)bf16_rne(dw1[(size_t)k * DW + col]) : 0;
    } else if (e < CIN1_E + CIN2_E + D1_E + D2_E) {
      int e2 = e - CIN1_E - CIN2_E - D1_E;
      int ksg = e2 / (WCOL * 32), r = e2 - ksg * (WCOL * 32);
      int col = r >> 5, kk = r & 31;
      int k = ksg * 32 + kk;
      wpd2[e2] = (k < DW && col < DW) ? (u16)bf16_rne(dw2[(size_t)k * DW + col]) : 0;
    } else if (e < PREP_E) {
      gstat[e - CIN1_E - CIN2_E - D1_E - D2_E] = 0.f;
    }
  }
}

// ---------------------------------------------------------------------------
// Fused CIN layer1+layer2, SPLIT-K over m. Grid 1024 x 4 waves = 4096 waves
// = 4 waves/SIMD (R20 measured: T=1 geometry is VALU-floor-bound at 57us with
// 61 VALU/step for 2 MFMA; R3's T=2 has 4 MFMA/step but only 2048 waves).
// Split-K mints 4096 waves AT T=2: wave(oh,kh) = 4 samples x 64 o (2 nt),
// m-range kh*20..kh*20+19 (m=39 = zero-pad x0 -> contributes exactly 0;
// its B over-read lands in the adjacent FINITE packed-weight region).
// Per step: 4 MFMA, ~26 VALU (a-build 16 shared across 2 nt, imm-offset xv
// loads via full m-unroll, 2 B addr adds). Pipe floors: MFMA 29us, VALU 14us,
// L1-B 28us.
// Partial acc combined via 32KB LDS exchange: wave donates its non-owned
// pair (pair index = kh) to slot [oh*2+pair], sibling adds -> each wave owns
// one FULL pair and runs the R3-proven epilogue for it.
// LDS: exch 32KB + s1b 8KB = 40KB -> exactly 4 blocks/CU.
// Lane: col=lane&31, khalf=lane>>5, si=(lane>>4)&1, d=lane&15.
// C/D: col=lane&31, row=(r&3)+8*(r>>2)+4*khalf -> si2=r>>3,
// dd=(r&3)+8*((r>>2)&1)+4*khalf.
// ---------------------------------------------------------------------------
__global__ __launch_bounds__(256) void k_cin_f(
    const u16* __restrict__ flatb, const u16* __restrict__ wp1,
    const u16* __restrict__ wp2, const float* __restrict__ bias1,
    const float* __restrict__ bias2, float* __restrict__ res) {
  __shared__ __align__(16) float exch[4][32][64];   // 32 KB acc exchange
  __shared__ __align__(16) u16 s1b[4 * 16 * 64];    // 8 KB swizzled nxt
  int t = threadIdx.x;
  int w = t >> 6, lane = t & 63;
  int oh = w & 1, kh = w >> 1;          // o-half, k-half
  int col = lane & 31, khalf = lane >> 5;
  int si = (lane >> 4) & 1, d = lane & 15;
  int b0 = blockIdx.x * 4;
  const u16* fb  = flatb + (size_t)(b0 + si) * AK1;
  const u16* fbm = fb + kh * 20 * 16;   // this wave's m-range base

  f32x16 acc[2][2];
#pragma unroll
  for (int p = 0; p < 2; p++)
#pragma unroll
    for (int nt = 0; nt < 2; nt++)
#pragma unroll
      for (int r = 0; r < 16; r++) acc[p][nt][r] = 0.f;

  // ---------------- layer 1: sq outer, m inner (20 m incl pad) ----------
  const u16* wb1 = wp1 + (size_t)(oh * 64 + col) * 16 + khalf * 8
                       + (size_t)kh * 20 * 3 * 2048;
#pragma unroll 1
  for (int sq = 0; sq < 3; sq++) {
    f32x2 sp[2][4];
#pragma unroll
    for (int p = 0; p < 2; p++)
#pragma unroll
      for (int w4 = 0; w4 < 4; w4++) {
        int h0 = sq * 16 + khalf * 8 + 2 * w4, h1 = h0 + 1;
        float f0 = (h0 < NF) ? bf2f(fb[p * 1280 + h0 * 16 + d]) : 0.f;
        float f1 = (h1 < NF) ? bf2f(fb[p * 1280 + h1 * 16 + d]) : 0.f;
        sp[p][w4] = (f32x2){f0, f1};
      }
    const u16* wbs = wb1 + (size_t)sq * 2048;
    short8 bc0 = *(const short8*)(wbs);
    short8 bc1 = *(const short8*)(wbs + 512);
    float xc0 = bf2f(fbm[d]), xc1 = bf2f(fbm[1280 + d]);
#pragma unroll
    for (int mj = 0; mj < 20; mj++) {
      // prefetch m+1 (last prefetch unused; lands in allocated ws)
      short8 bn0 = *(const short8*)(wbs + (size_t)(mj + 1) * 6144);
      short8 bn1 = *(const short8*)(wbs + (size_t)(mj + 1) * 6144 + 512);
      float xn0 = bf2f(fbm[(mj + 1) * 16 + d]);
      float xn1 = bf2f(fbm[1280 + (mj + 1) * 16 + d]);
      __builtin_amdgcn_s_setprio(1);
      {
        union { unsigned u[4]; short8 v; } a;
        f32x2 xv2 = (f32x2){xc0, xc0};
#pragma unroll
        for (int w4 = 0; w4 < 4; w4++) {
          f32x2 pr = sp[0][w4] * xv2;
          a.u[w4] = pack_hi2(pr[0], pr[1]);
        }
        acc[0][0] = __builtin_amdgcn_mfma_f32_32x32x16_bf16(a.v, bc0, acc[0][0], 0, 0, 0);
        acc[0][1] = __builtin_amdgcn_mfma_f32_32x32x16_bf16(a.v, bc1, acc[0][1], 0, 0, 0);
      }
      {
        union { unsigned u[4]; short8 v; } a;
        f32x2 xv2 = (f32x2){xc1, xc1};
#pragma unroll
        for (int w4 = 0; w4 < 4; w4++) {
          f32x2 pr = sp[1][w4] * xv2;
          a.u[w4] = pack_hi2(pr[0], pr[1]);
        }
        acc[1][0] = __builtin_amdgcn_mfma_f32_32x32x16_bf16(a.v, bc0, acc[1][0], 0, 0, 0);
        acc[1][1] = __builtin_amdgcn_mfma_f32_32x32x16_bf16(a.v, bc1, acc[1][1], 0, 0, 0);
      }
      __builtin_amdgcn_s_setprio(0);
      bc0 = bn0; bc1 = bn1; xc0 = xn0; xc1 = xn1;
    }
  }

  // exchange + epilogue helpers (ACC identity static at call sites)
  auto xstore = [&](const f32x16 (&A)[2], int slot) {
#pragma unroll
    for (int nt = 0; nt < 2; nt++)
#pragma unroll
      for (int r = 0; r < 16; r++)
        exch[slot][nt * 16 + r][lane] = A[nt][r];
  };
  auto xadd = [&](f32x16 (&A)[2], int slot) {
#pragma unroll
    for (int nt = 0; nt < 2; nt++)
#pragma unroll
      for (int r = 0; r < 16; r++)
        A[nt][r] += exch[slot][nt * 16 + r][lane];
  };
  auto epi1 = [&](const f32x16 (&A)[2], int P) {
    if (oh == 0) {                      // relu -> s1b (o<64)
#pragma unroll
      for (int nt = 0; nt < 2; nt++) {
        int o = nt * 32 + col;
        float bi = bias1[o];
#pragma unroll
        for (int r = 0; r < 16; r++) {
          int smp = P * 2 + (r >> 3);
          int dd = (r & 3) + 8 * ((r >> 2) & 1) + 4 * khalf;
          float v = fmaxf(A[nt][r] + bi, 0.f);
          int ix = (((smp * 16 + dd) * 64) + o) ^ ((dd & 7) << 3);
          s1b[ix] = (u16)bf16_rne(v);
        }
      }
    } else {                            // hi1 d-sum -> res[o-64]
#pragma unroll
      for (int nt = 0; nt < 2; nt++) {
        int o = 64 + nt * 32 + col;
        float bi = bias1[o];
        float q0 = 0.f, q1 = 0.f;
#pragma unroll
        for (int r = 0; r < 8; r++)  q0 += fmaxf(A[nt][r] + bi, 0.f);
#pragma unroll
        for (int r = 8; r < 16; r++) q1 += fmaxf(A[nt][r] + bi, 0.f);
        q0 += __shfl_xor(q0, 32);
        q1 += __shfl_xor(q1, 32);
        if (khalf == 0) {
          res[(size_t)(b0 + P * 2) * 192 + (o - 64)] = q0;
          res[(size_t)(b0 + P * 2 + 1) * 192 + (o - 64)] = q1;
        }
      }
    }
  };
  auto epi2 = [&](const f32x16 (&A)[2], int P) {
#pragma unroll
    for (int nt = 0; nt < 2; nt++) {
      int o = oh * 64 + nt * 32 + col;
      float bi = bias2[o];
      float q0 = 0.f, q1 = 0.f;
#pragma unroll
      for (int r = 0; r < 8; r++)  q0 += fmaxf(A[nt][r] + bi, 0.f);
#pragma unroll
      for (int r = 8; r < 16; r++) q1 += fmaxf(A[nt][r] + bi, 0.f);
      q0 += __shfl_xor(q0, 32);
      q1 += __shfl_xor(q1, 32);
      if (khalf == 0) {
        res[(size_t)(b0 + P * 2) * 192 + 64 + o] = q0;
        res[(size_t)(b0 + P * 2 + 1) * 192 + 64 + o] = q1;
      }
    }
  };

  // ---- L1 split-K combine: donate non-owned pair, own pair = kh ----
  if (kh == 0) xstore(acc[1], oh * 2 + 1); else xstore(acc[0], oh * 2);
  __syncthreads();
  if (kh == 0) { xadd(acc[0], oh * 2);     epi1(acc[0], 0); }
  else         { xadd(acc[1], oh * 2 + 1); epi1(acc[1], 1); }
  __syncthreads();                       // s1b ready; exch reusable

  // ---------------- layer 2: sq outer, m inner ----------------
#pragma unroll
  for (int p = 0; p < 2; p++)
#pragma unroll
    for (int nt = 0; nt < 2; nt++)
#pragma unroll
      for (int r = 0; r < 16; r++) acc[p][nt][r] = 0.f;

  const u16* wb2 = wp2 + (size_t)(oh * 64 + col) * 16 + khalf * 8
                       + (size_t)kh * 20 * 4 * 2048;
#pragma unroll 1
  for (int sq = 0; sq < 4; sq++) {
    f32x2 sp[2][4];
#pragma unroll
    for (int p = 0; p < 2; p++) {
      int smp = p * 2 + si;
      int ix = ((smp * 16 + d) * 64 + sq * 16 + khalf * 8) ^ ((d & 7) << 3);
      union { short8 v; u16 e[8]; } vv;
      vv.v = *(const short8*)(s1b + ix);
#pragma unroll
      for (int w4 = 0; w4 < 4; w4++)
        sp[p][w4] = (f32x2){bf2f(vv.e[2 * w4]), bf2f(vv.e[2 * w4 + 1])};
    }
    const u16* wbs = wb2 + (size_t)sq * 2048;
    short8 bc0 = *(const short8*)(wbs);
    short8 bc1 = *(const short8*)(wbs + 512);
    float xc0 = bf2f(fbm[d]), xc1 = bf2f(fbm[1280 + d]);
#pragma unroll
    for (int mj = 0; mj < 20; mj++) {
      short8 bn0 = *(const short8*)(wbs + (size_t)(mj + 1) * 8192);
      short8 bn1 = *(const short8*)(wbs + (size_t)(mj + 1) * 8192 + 512);
      float xn0 = bf2f(fbm[(mj + 1) * 16 + d]);
      float xn1 = bf2f(fbm[1280 + (mj + 1) * 16 + d]);
      __builtin_amdgcn_s_setprio(1);
      {
        union { unsigned u[4]; short8 v; } a;
        f32x2 xv2 = (f32x2){xc0, xc0};
#pragma unroll
        for (int w4 = 0; w4 < 4; w4++) {
          f32x2 pr = sp[0][w4] * xv2;
          a.u[w4] = pack_hi2(pr[0], pr[1]);
        }
        acc[0][0] = __builtin_amdgcn_mfma_f32_32x32x16_bf16(a.v, bc0, acc[0][0], 0, 0, 0);
        acc[0][1] = __builtin_amdgcn_mfma_f32_32x32x16_bf16(a.v, bc1, acc[0][1], 0, 0, 0);
      }
      {
        union { unsigned u[4]; short8 v; } a;
        f32x2 xv2 = (f32x2){xc1, xc1};
#pragma unroll
        for (int w4 = 0; w4 < 4; w4++) {
          f32x2 pr = sp[1][w4] * xv2;
          a.u[w4] = pack_hi2(pr[0], pr[1]);
        }
        acc[1][0] = __builtin_amdgcn_mfma_f32_32x32x16_bf16(a.v, bc0, acc[1][0], 0, 0, 0);
        acc[1][1] = __builtin_amdgcn_mfma_f32_32x32x16_bf16(a.v, bc1, acc[1][1], 0, 0, 0);
      }
      __builtin_amdgcn_s_setprio(0);
      bc0 = bn0; bc1 = bn1; xc0 = xn0; xc1 = xn1;
    }
  }

  // ---- L2 split-K combine + epilogue ----
  if (kh == 0) xstore(acc[1], oh * 2 + 1); else xstore(acc[0], oh * 2);
  __syncthreads();
  if (kh == 0) { xadd(acc[0], oh * 2);     epi2(acc[0], 0); }
  else         { xadd(acc[1], oh * 2 + 1); epi2(acc[1], 1); }
}

// ---------------------------------------------------------------------------
// Deep-tower GEMM via MFMA (unchanged). Grid (M/64, 13), wave = 16 rows
// x 32 cols. BN_A folds previous layer's BN finalize; fused BN stats.
// ---------------------------------------------------------------------------
template <bool BN_A, int NKS, int KREAL, int AK>
__global__ __launch_bounds__(256) void k_gemm_mfma(
    const u16* __restrict__ Abf, const float* __restrict__ Af32,
    const u16* __restrict__ wp, const float* __restrict__ bias,
    const float* __restrict__ gsIn, const float* __restrict__ gs2In,
    const float* __restrict__ bng, const float* __restrict__ bnb,
    float* __restrict__ C, float* __restrict__ gs, float* __restrict__ gs2) {
  __shared__ float lsS[NKS * 32], lsH[NKS * 32];
  __shared__ float lred[64];
  int t = threadIdx.x;
  if (BN_A) {
    for (int c = t; c < NKS * 32; c += 256) {
      float sc = 0.f, sh = 0.f;
      if (c < DW) {
        float m = gsIn[c] * (1.f / BATCH);
        float var = gs2In[c] * (1.f / BATCH) - m * m;
        sc = bng[c] * rsqrtf(var + BN_EPS);
        sh = bnb[c] - m * sc;
      }
      lsS[c] = sc; lsH[c] = sh;
    }
  }
  if (t < 64) lred[t] = 0.f;
  __syncthreads();

  int w = t >> 6, lane = t & 63;
  int nl = lane & 15, q = lane >> 4;
  int row = blockIdx.x * 64 + w * 16 + nl;
  int c0 = blockIdx.y * 32;
  f32x4 acc[2];
  acc[0] = (f32x4){0.f, 0.f, 0.f, 0.f};
  acc[1] = (f32x4){0.f, 0.f, 0.f, 0.f};

  short8 araw[2]; f32x4 fraw0[2], fraw1[2]; short8 braw[2][2];
  auto loadA_raw = [&](int ksg, int buf) {
    int kb = ksg * 32 + q * 8;
    if (!BN_A) {
      araw[buf] = *(const short8*)(Abf + (size_t)row * AK + kb);
    } else {
      if (kb + 8 <= KREAL) {
        fraw0[buf] = *(const f32x4*)(Af32 + (size_t)row * KREAL + kb);
        fraw1[buf] = *(const f32x4*)(Af32 + (size_t)row * KREAL + kb + 4);
      } else {
        fraw0[buf] = (f32x4){0.f,0.f,0.f,0.f};
        fraw1[buf] = (f32x4){0.f,0.f,0.f,0.f};
      }
    }
    const u16* wb = wp + (size_t)ksg * (WCOL * 32) + (size_t)(c0 + nl) * 32 + q * 8;
    braw[buf][0] = *(const short8*)wb;
    braw[buf][1] = *(const short8*)(wb + 16 * 32);
  };
  auto cookA = [&](int ksg, int buf) -> short8 {
    if (!BN_A) return araw[buf];
    int kb = ksg * 32 + q * 8;
    f32x4 s0 = *(const f32x4*)&lsS[kb], h0 = *(const f32x4*)&lsH[kb];
    f32x4 s1 = *(const f32x4*)&lsS[kb + 4], h1 = *(const f32x4*)&lsH[kb + 4];
    union { unsigned u[4]; short8 s; } a;
    float v0 = fmaxf(fmaf(fraw0[buf][0], s0[0], h0[0]), 0.f);
    float v1 = fmaxf(fmaf(fraw0[buf][1], s0[1], h0[1]), 0.f);
    float v2 = fmaxf(fmaf(fraw0[buf][2], s0[2], h0[2]), 0.f);
    float v3 = fmaxf(fmaf(fraw0[buf][3], s0[3], h0[3]), 0.f);
    float v4 = fmaxf(fmaf(fraw1[buf][0], s1[0], h1[0]), 0.f);
    float v5 = fmaxf(fmaf(fraw1[buf][1], s1[1], h1[1]), 0.f);
    float v6 = fmaxf(fmaf(fraw1[buf][2], s1[2], h1[2]), 0.f);
    float v7 = fmaxf(fmaf(fraw1[buf][3], s1[3], h1[3]), 0.f);
    a.u[0] = bf16_rne(v0) | (bf16_rne(v1) << 16);
    a.u[1] = bf16_rne(v2) | (bf16_rne(v3) << 16);
    a.u[2] = bf16_rne(v4) | (bf16_rne(v5) << 16);
    a.u[3] = bf16_rne(v6) | (bf16_rne(v7) << 16);
    return a.s;
  };

  loadA_raw(0, 0);
#pragma unroll 4
  for (int ksg = 0; ksg < NKS; ksg++) {
    int cur = ksg & 1;
    if (ksg + 1 < NKS) loadA_raw(ksg + 1, cur ^ 1);
    short8 afr = cookA(ksg, cur);
    acc[0] = __builtin_amdgcn_mfma_f32_16x16x32_bf16(afr, braw[cur][0], acc[0], 0, 0, 0);
    acc[1] = __builtin_amdgcn_mfma_f32_16x16x32_bf16(afr, braw[cur][1], acc[1], 0, 0, 0);
  }

  int rbase = blockIdx.x * 64 + w * 16 + q * 4;
#pragma unroll
  for (int nt = 0; nt < 2; nt++) {
    int col = c0 + nt * 16 + nl;
    if (col < DW) {
      float bi = bias[col];
      float s = 0.f, s2 = 0.f;
#pragma unroll
      for (int r = 0; r < 4; r++) {
        float v = acc[nt][r] + bi;
        C[(size_t)(rbase + r) * DW + col] = v;
        s += v; s2 = fmaf(v, v, s2);
      }
      s += __shfl_xor(s, 16); s2 += __shfl_xor(s2, 16);
      s += __shfl_xor(s, 32); s2 += __shfl_xor(s2, 32);
      if (q == 0) {
        atomicAdd(&lred[nt * 16 + nl], s);
        atomicAdd(&lred[32 + nt * 16 + nl], s2);
      }
    }
  }
  __syncthreads();
  if (t < 32) {
    int col = c0 + t;
    if (col < DW) atomicAdd(&gs[col], lred[t]);
  } else if (t < 64) {
    int col = c0 + t - 32;
    if (col < DW) atomicAdd(&gs2[col], lred[t]);
  }
}

// ---------------------------------------------------------------------------
// Final concat + dot, BN2 finalize folded in-block.
// ---------------------------------------------------------------------------
__global__ __launch_bounds__(256) void k_final(const float* __restrict__ lp,
    const float* __restrict__ res, const float* __restrict__ y2,
    const float* __restrict__ gB, const float* __restrict__ gB2,
    const float* __restrict__ g2, const float* __restrict__ bb2,
    const float* __restrict__ ow, const float* __restrict__ ob,
    float* __restrict__ out) {
  __shared__ float lsS[DW], lsH[DW];
  int t = threadIdx.x;
  for (int c = t; c < DW; c += 256) {
    float m = gB[c] * (1.f / BATCH);
    float var = gB2[c] * (1.f / BATCH) - m * m;
    float sc = g2[c] * rsqrtf(var + BN_EPS);
    lsS[c] = sc;
    lsH[c] = bb2[c] - m * sc;
  }
  __syncthreads();
  int lane = t & 63, w = t >> 6;
  int b = blockIdx.x * 4 + w;
  float acc = 0.f;
  for (int j = lane; j < 593; j += 64) {
    float v;
    if (j == 0)       v = lp[b];
    else if (j < 193) v = res[(size_t)b * 192 + (j - 1)];
    else {
      int c = j - 193;
      v = fmaxf(fmaf(y2[(size_t)b * DW + c], lsS[c], lsH[c]), 0.f);
    }
    acc = fmaf(v, ow[j], acc);
  }
#pragma unroll
  for (int k = 1; k < 64; k <<= 1) acc += __shfl_xor(acc, k);
  if (lane == 0) out[b] = acc + ob[0];
}

// ---------------------------------------------------------------------------
extern "C" void kernel_launch(void* const* d_in, const int* in_sizes, int n_in,
                              void* d_out, int out_size, void* d_ws, size_t ws_size,
                              hipStream_t stream) {
  const int*   feat_index = (const int*)d_in[0];
  const float* emb = (const float*)d_in[2];
  const float* lw  = (const float*)d_in[3];
  const float* lb  = (const float*)d_in[4];
  const float* w1  = (const float*)d_in[5];
  const float* b1  = (const float*)d_in[6];
  const float* w2  = (const float*)d_in[7];
  const float* b2  = (const float*)d_in[8];
  const float* dw1 = (const float*)d_in[9];
  const float* db1 = (const float*)d_in[10];
  const float* g1  = (const float*)d_in[11];
  const float* bb1 = (const float*)d_in[12];
  const float* dw2 = (const float*)d_in[13];
  const float* db2 = (const float*)d_in[14];
  const float* g2  = (const float*)d_in[15];
  const float* bb2 = (const float*)d_in[16];
  const float* ow  = (const float*)d_in[17];
  const float* ob  = (const float*)d_in[18];

  float* ws   = (float*)d_ws;
  u16*  flatb = (u16*)ws;                  // 4096*640 bf16 = 1,310,720 f
  float* y1   = ws + 1310720;              // 4096*400 f32
  float* res  = ws + 2949120;              // 4096*192 f32
  float* lp   = ws + 3735552;              // 4096
  float* gA   = ws + 3741248;              // 400 sum
  float* gA2  = gA + 400;
  float* gB   = gA2 + 400;
  float* gB2  = gB + 400;                  // gstat: 1600 contiguous
  float* y2   = ws + 3742848;              // 4096*400 f32
  u16*  wp1   = (u16*)(ws + 5381248);      // 239,616 bf16 = 119,808 f
  u16*  wp2   = (u16*)(ws + 5501056);      // 319,488 bf16 = 159,744 f
  u16*  wpd1  = (u16*)(ws + 5660800);      // 266,240 bf16 = 133,120 f
  u16*  wpd2  = (u16*)(ws + 5793920);      // 173,056 bf16 -> ends 5,880,448 f
  float* out  = (float*)d_out;

  k_gp<<<GATH_B + PREP_B, 256, 0, stream>>>(feat_index, emb, lw, lb, w1, w2,
      dw1, dw2, flatb, lp, wp1, wp2, wpd1, wpd2, gA);
  k_cin_f<<<1024, 256, 0, stream>>>(flatb, wp1, wp2, b1, b2, res);
  k_gemm_mfma<false, NKS1, IN_DIM, AK1><<<dim3(BATCH / 64, 13), 256, 0, stream>>>(
      flatb, nullptr, wpd1, db1, nullptr, nullptr, nullptr, nullptr, y1, gA, gA2);
  k_gemm_mfma<true, NKS2, DW, 0><<<dim3(BATCH / 64, 13), 256, 0, stream>>>(
      nullptr, y1, wpd2, db2, gA, gA2, g1, bb1, y2, gB, gB2);
  k_final<<<BATCH / 4, 256, 0, stream>>>(lp, res, y2, gB, gB2, g2, bb2, ow, ob, out);
}

// Round 22
// 245.002 us; speedup vs baseline: 1.0977x; 1.0977x over previous
//
#include <hip/hip_runtime.h>

// Problem constants
#define BATCH   4096
#define NF      39          // num_field
#define ED      16          // embedding size
#define IN_DIM  624         // NF*ED
#define DW      400
#define BN_EPS  1e-5f
#define AK1     640         // padded deep K for layer 1 input (624 -> 640)
#define NKS1    20          // AK1/32
#define NKS2    13          // 400 -> 416 padded
#define WCOL    416         // padded deep-weight column count
#define NK1     117         // CIN layer-1 k16 steps: 39 m * 48 h / 16 (h padded 39->48)
#define NK2     156         // CIN layer-2 k16 steps: 39 m * 64 h / 16

typedef __attribute__((ext_vector_type(8))) short short8;
typedef __attribute__((ext_vector_type(16))) float f32x16;
typedef __attribute__((ext_vector_type(4))) float f32x4;
typedef __attribute__((ext_vector_type(2))) float f32x2;
typedef unsigned short u16;

__device__ inline unsigned pack_hi2(float a, float b) {
  return __builtin_amdgcn_perm(__float_as_uint(b), __float_as_uint(a), 0x07060302u);
}
__device__ inline unsigned bf16_rne(float f) {
  unsigned u = __float_as_uint(f);
  u += 0x7fff + ((u >> 16) & 1);
  return u >> 16;
}
__device__ inline float bf2f(u16 v) { return __uint_as_float((unsigned)v << 16); }

#define CIN1_E (NK1 * 2048)          // 239616
#define CIN2_E (NK2 * 2048)          // 319488
#define D1_E  (NKS1 * WCOL * 32)     // 266240
#define D2_E  (NKS2 * WCOL * 32)     // 173056
#define PREP_E (CIN1_E + CIN2_E + D1_E + D2_E + 1600)
#define PREP_B ((PREP_E + 255) / 256)
#define GATH_B (BATCH / 4)

// ---------------------------------------------------------------------------
// Merged: blocks < GATH_B gather embeddings (wave per sample, no barriers);
// rest pack weights into B-fragment layout and zero BN-stat accumulators.
// CIN pack layout (32x32x16): wp[k16][col 128][kk 16]; lane reads 8 bf16 at
// col*16 + khalf*8.
//   layer1: k = m*48 + h  (h<48, zero for h>=39)  -> k16 = m*3 + s, h=s*16+kk
//   layer2: k = m*64 + h  (h<64)
// ---------------------------------------------------------------------------
__global__ __launch_bounds__(256) void k_gp(const int* __restrict__ idx,
    const float* __restrict__ emb, const float* __restrict__ lw,
    const float* __restrict__ lb, const float* __restrict__ w1,
    const float* __restrict__ w2, const float* __restrict__ dw1,
    const float* __restrict__ dw2, u16* __restrict__ flatb,
    float* __restrict__ lp, u16* __restrict__ wp1, u16* __restrict__ wp2,
    u16* __restrict__ wpd1, u16* __restrict__ wpd2, float* __restrict__ gstat) {
  int t = threadIdx.x;
  if (blockIdx.x < GATH_B) {
    int lane = t & 63;
    int b = blockIdx.x * 4 + (t >> 6);
    int sj = (lane < NF) ? idx[b * NF + lane] : 0;
    float acc = 0.f;
#pragma unroll
    for (int i = 0; i < 10; i++) {
      int e = lane + i * 64;
      if (e < IN_DIM) {
        int f = e >> 4;
        int row = __shfl(sj, f);
        float v = emb[(size_t)row * ED + (e & 15)];
        flatb[(size_t)b * AK1 + e] = (u16)bf16_rne(v);
        acc = fmaf(v, lw[e], acc);
      } else {
        flatb[(size_t)b * AK1 + e] = 0;
      }
    }
#pragma unroll
    for (int k = 1; k < 64; k <<= 1) acc += __shfl_xor(acc, k);
    if (lane == 0) lp[b] = acc + lb[0];
  } else {
    int e = (blockIdx.x - GATH_B) * 256 + t;
    if (e < CIN1_E) {
      int k16 = e >> 11, r = e & 2047, col = r >> 4, kk = r & 15;
      int mg = k16 / 3, sg = k16 - mg * 3;      // m = mg, h = sg*16+kk
      int h = sg * 16 + kk;
      wp1[e] = (h < NF) ? (u16)bf16_rne(w1[(size_t)col * (NF * NF) + h * NF + mg])
                        : (u16)0;
    } else if (e < CIN1_E + CIN2_E) {
      int e2 = e - CIN1_E;
      int k16 = e2 >> 11, r = e2 & 2047, col = r >> 4, kk = r & 15;
      int k = k16 * 16 + kk, h = k & 63, m = k >> 6;
      wp2[e2] = (u16)bf16_rne(w2[(size_t)col * (64 * NF) + h * NF + m]);
    } else if (e < CIN1_E + CIN2_E + D1_E) {
      int e2 = e - CIN1_E - CIN2_E;
      int ksg = e2 / (WCOL * 32), r = e2 - ksg * (WCOL * 32);
      int col = r >> 5, kk = r & 31;
      int k = ksg * 32 + kk;
      wpd1[e2] = (k < IN_DIM && col < DW) ? (u16)bf16_rne(dw1[(size_t)k * DW + col]) : 0;
    } else if (e < CIN1_E + CIN2_E + D1_E + D2_E) {
      int e2 = e - CIN1_E - CIN2_E - D1_E;
      int ksg = e2 / (WCOL * 32), r = e2 - ksg * (WCOL * 32);
      int col = r >> 5, kk = r & 31;
      int k = ksg * 32 + kk;
      wpd2[e2] = (k < DW && col < DW) ? (u16)bf16_rne(dw2[(size_t)k * DW + col]) : 0;
    } else if (e < PREP_E) {
      gstat[e - CIN1_E - CIN2_E - D1_E - D2_E] = 0.f;
    }
  }
}

// ---------------------------------------------------------------------------
// Fused CIN layer1+layer2 via 32x32x16 MFMA. Grid 512 blocks x 4 waves.
// Wave = 4 samples (2 pairs) x 64 o (2 n-tiles): sgrp = w&1 (sample quad),
// oh = w>>1 (o-half). REVERTED to the exact R3-measured config (81.5us,
// best of 6 structural variants):
//   R3  this kernel:                 81.5us  (T=2, 2 WG/CU)
//   R10/R17 T=1 (32 o/wave):         ~100us  (2 WG/CU)
//   R20 T=1 s-outer (VGPR 52):       102us   (3 WG/CU, VALU-floor ~57us)
//   R21 split-K (VGPR 132, 40KB):    109us   (1 WG/CU)
// Occupancy model fitted to all points: waves/SIMD = floor(256/(VGPR+accAGPR))
// -> T=2 (acc 64 AGPR) is hard-capped at 2 waves/SIMD; T=1 reaches 3 but is
// VALU-floor-bound. This config is the measured optimum of the design space.
// Lane: col=lane&31 (o), khalf=lane>>5 (k-subrange), si=(lane>>4)&1,
// d=lane&15 (A rows = 2 samples x 16 d per pair).
// Layer1 h padded to 48 (NK1=117, 25% fewer steps); layer2 h=64 (NK2=156).
// Layer1 o<64 output (nxt) handed to layer2 through a 16KB XOR-swizzled LDS
// buffer ([smp][d][h], u16 idx ^= (d&7)<<3) + one barrier — no HBM roundtrip.
// B prefetch: ring 3 / dist 2 (L1), ring 4 / dist 3 (L2); slot indices static
// (inner bodies of 9 / 12 steps). Ring over-reads past wp end are safe
// (land in the adjacent packed-weight regions, never consumed).
// C/D: col=lane&31, row=(r&3)+8*(r>>2)+4*khalf -> si2=r>>3,
// dd=(r&3)+8*((r>>2)&1)+4*khalf.
// ---------------------------------------------------------------------------
__global__ __launch_bounds__(256, 2) void k_cin_f(
    const u16* __restrict__ flatb, const u16* __restrict__ wp1,
    const u16* __restrict__ wp2, const float* __restrict__ bias1,
    const float* __restrict__ bias2, float* __restrict__ res) {
  __shared__ __align__(16) u16 s1b[8 * 16 * 64];   // [smp][d][h=o'] swizzled
  int t = threadIdx.x;
  int w = t >> 6, lane = t & 63;
  int sgrp = w & 1, oh = w >> 1;
  int col = lane & 31, khalf = lane >> 5;
  int si = (lane >> 4) & 1, d = lane & 15;
  int b0 = blockIdx.x * 8 + sgrp * 4;
  const u16* fb = flatb + (size_t)(b0 + si) * AK1;   // pair0; pair1 at +1280

  // ---------------- layer 1 ----------------
  // s1 (x0) as f32 pairs: sp1[pair][s-group][w4]
  f32x2 sp1[2][3][4];
#pragma unroll
  for (int p = 0; p < 2; p++)
#pragma unroll
    for (int s = 0; s < 3; s++)
#pragma unroll
      for (int w4 = 0; w4 < 4; w4++) {
        int h0 = s * 16 + khalf * 8 + 2 * w4;
        int h1 = h0 + 1;
        float f0 = (h0 < NF) ? bf2f(fb[p * 1280 + h0 * 16 + d]) : 0.f;
        float f1 = (h1 < NF) ? bf2f(fb[p * 1280 + h1 * 16 + d]) : 0.f;
        sp1[p][s][w4] = (f32x2){f0, f1};
      }

  const u16* wb1 = wp1 + (size_t)(oh * 64 + col) * 16 + khalf * 8;
  short8 bfr[3][2];                       // ring 3, distance 2
#pragma unroll
  for (int k16 = 0; k16 < 2; k16++)
#pragma unroll
    for (int nt = 0; nt < 2; nt++)
      bfr[k16][nt] = *(const short8*)(wb1 + (size_t)k16 * 2048 + nt * 512);

  f32x16 acc[2][2];
#pragma unroll
  for (int p = 0; p < 2; p++)
#pragma unroll
    for (int nt = 0; nt < 2; nt++)
#pragma unroll
      for (int r = 0; r < 16; r++) acc[p][nt][r] = 0.f;

  float xv[2] = {bf2f(fb[d]), bf2f(fb[1280 + d])};
  float xvn[2];

#pragma unroll 1
  for (int mg = 0; mg < 13; mg++) {       // 13 groups x 9 steps (3 m-fields)
#pragma unroll
    for (int j = 0; j < 9; j++) {
      int k16 = mg * 9 + j;
      int s = j % 3;                      // static: consume slot s
      if (s == 0) {                       // prefetch next m's x0 value
        int mn = mg * 3 + j / 3 + 1;      // m=39 -> zero-padded region, safe
        xvn[0] = bf2f(fb[mn * 16 + d]);
        xvn[1] = bf2f(fb[1280 + mn * 16 + d]);
      }
      {                                   // prefetch k16+2 into slot (s+2)%3
        const u16* wbp = wb1 + (size_t)(k16 + 2) * 2048;
#pragma unroll
        for (int nt = 0; nt < 2; nt++)
          bfr[(s + 2) % 3][nt] = *(const short8*)(wbp + nt * 512);
      }
      __builtin_amdgcn_s_setprio(1);
#pragma unroll
      for (int p = 0; p < 2; p++) {
        union { unsigned u[4]; short8 v; } a;
        f32x2 xv2 = (f32x2){xv[p], xv[p]};
#pragma unroll
        for (int w4 = 0; w4 < 4; w4++) {
          f32x2 pr = sp1[p][s][w4] * xv2; // v_pk_mul_f32
          a.u[w4] = pack_hi2(pr[0], pr[1]);
        }
#pragma unroll
        for (int nt = 0; nt < 2; nt++)
          acc[p][nt] = __builtin_amdgcn_mfma_f32_32x32x16_bf16(
              a.v, bfr[s][nt], acc[p][nt], 0, 0, 0);
      }
      __builtin_amdgcn_s_setprio(0);
      if (s == 2) { xv[0] = xvn[0]; xv[1] = xvn[1]; }
    }
  }

  // layer-1 epilogue: oh==0 -> relu to LDS (nxt), oh==1 -> d-sum to res (hi1)
  if (oh == 0) {
#pragma unroll
    for (int p = 0; p < 2; p++)
#pragma unroll
      for (int nt = 0; nt < 2; nt++) {
        int o = nt * 32 + col;            // o in [0,64)
        float bi = bias1[o];
#pragma unroll
        for (int r = 0; r < 16; r++) {
          int smp = sgrp * 4 + p * 2 + (r >> 3);
          int dd = (r & 3) + 8 * ((r >> 2) & 1) + 4 * khalf;
          float v = fmaxf(acc[p][nt][r] + bi, 0.f);
          int ix = (((smp * 16 + dd) * 64) + o) ^ ((dd & 7) << 3);
          s1b[ix] = (u16)bf16_rne(v);
        }
      }
  } else {
#pragma unroll
    for (int p = 0; p < 2; p++)
#pragma unroll
      for (int nt = 0; nt < 2; nt++) {
        int o = 64 + nt * 32 + col;       // o in [64,128)
        float bi = bias1[o];
        float p0 = 0.f, p1 = 0.f;
#pragma unroll
        for (int r = 0; r < 8; r++)  p0 += fmaxf(acc[p][nt][r] + bi, 0.f);
#pragma unroll
        for (int r = 8; r < 16; r++) p1 += fmaxf(acc[p][nt][r] + bi, 0.f);
        p0 += __shfl_xor(p0, 32);         // add complementary d-half
        p1 += __shfl_xor(p1, 32);
        if (khalf == 0) {
          res[(size_t)(b0 + p * 2) * 192 + (o - 64)] = p0;
          res[(size_t)(b0 + p * 2 + 1) * 192 + (o - 64)] = p1;
        }
      }
  }

  // layer-2 B prologue (issued before barrier; barrier drains vmcnt, fine)
  const u16* wb2 = wp2 + (size_t)(oh * 64 + col) * 16 + khalf * 8;
  short8 bq[4][2];                        // ring 4, distance 3
#pragma unroll
  for (int k16 = 0; k16 < 3; k16++)
#pragma unroll
    for (int nt = 0; nt < 2; nt++)
      bq[k16][nt] = *(const short8*)(wb2 + (size_t)k16 * 2048 + nt * 512);

  __syncthreads();

  // ---------------- layer 2 ----------------
  // s1 = relu(layer1(o<64)) from swizzled LDS: sp2[pair][s-group][w4]
  f32x2 sp2[2][4][4];
#pragma unroll
  for (int p = 0; p < 2; p++) {
    int smp = sgrp * 4 + p * 2 + si;
#pragma unroll
    for (int s = 0; s < 4; s++) {
      int ix = ((smp * 16 + d) * 64 + s * 16 + khalf * 8) ^ ((d & 7) << 3);
      union { short8 v; u16 e[8]; } vv;
      vv.v = *(const short8*)(s1b + ix);
#pragma unroll
      for (int w4 = 0; w4 < 4; w4++)
        sp2[p][s][w4] = (f32x2){bf2f(vv.e[2 * w4]), bf2f(vv.e[2 * w4 + 1])};
    }
  }

#pragma unroll
  for (int p = 0; p < 2; p++)
#pragma unroll
    for (int nt = 0; nt < 2; nt++)
#pragma unroll
      for (int r = 0; r < 16; r++) acc[p][nt][r] = 0.f;

  xv[0] = bf2f(fb[d]);
  xv[1] = bf2f(fb[1280 + d]);

#pragma unroll 1
  for (int mg = 0; mg < 13; mg++) {       // 13 groups x 12 steps (3 m-fields)
#pragma unroll
    for (int j = 0; j < 12; j++) {
      int k16 = mg * 12 + j;
      int s = j & 3;                      // static: consume slot s
      if (s == 0) {
        int mn = mg * 3 + (j >> 2) + 1;   // m=39 -> zero pad, safe
        xvn[0] = bf2f(fb[mn * 16 + d]);
        xvn[1] = bf2f(fb[1280 + mn * 16 + d]);
      }
      {                                   // prefetch k16+3 into slot (j+3)&3
        const u16* wbp = wb2 + (size_t)(k16 + 3) * 2048;
#pragma unroll
        for (int nt = 0; nt < 2; nt++)
          bq[(j + 3) & 3][nt] = *(const short8*)(wbp + nt * 512);
      }
      __builtin_amdgcn_s_setprio(1);
#pragma unroll
      for (int p = 0; p < 2; p++) {
        union { unsigned u[4]; short8 v; } a;
        f32x2 xv2 = (f32x2){xv[p], xv[p]};
#pragma unroll
        for (int w4 = 0; w4 < 4; w4++) {
          f32x2 pr = sp2[p][s][w4] * xv2;
          a.u[w4] = pack_hi2(pr[0], pr[1]);
        }
#pragma unroll
        for (int nt = 0; nt < 2; nt++)
          acc[p][nt] = __builtin_amdgcn_mfma_f32_32x32x16_bf16(
              a.v, bq[s][nt], acc[p][nt], 0, 0, 0);
      }
      __builtin_amdgcn_s_setprio(0);
      if (s == 3) { xv[0] = xvn[0]; xv[1] = xvn[1]; }
    }
  }

  // layer-2 epilogue: d-sum -> res[64 + o]
#pragma unroll
  for (int p = 0; p < 2; p++)
#pragma unroll
    for (int nt = 0; nt < 2; nt++) {
      int o = oh * 64 + nt * 32 + col;
      float bi = bias2[o];
      float p0 = 0.f, p1 = 0.f;
#pragma unroll
      for (int r = 0; r < 8; r++)  p0 += fmaxf(acc[p][nt][r] + bi, 0.f);
#pragma unroll
      for (int r = 8; r < 16; r++) p1 += fmaxf(acc[p][nt][r] + bi, 0.f);
      p0 += __shfl_xor(p0, 32);
      p1 += __shfl_xor(p1, 32);
      if (khalf == 0) {
        res[(size_t)(b0 + p * 2) * 192 + 64 + o] = p0;
        res[(size_t)(b0 + p * 2 + 1) * 192 + 64 + o] = p1;
      }
    }
}

// ---------------------------------------------------------------------------
// Deep-tower GEMM via MFMA (unchanged). Grid (M/64, 13), wave = 16 rows
// x 32 cols. BN_A folds previous layer's BN finalize; fused BN stats.
// ---------------------------------------------------------------------------
template <bool BN_A, int NKS, int KREAL, int AK>
__global__ __launch_bounds__(256) void k_gemm_mfma(
    const u16* __restrict__ Abf, const float* __restrict__ Af32,
    const u16* __restrict__ wp, const float* __restrict__ bias,
    const float* __restrict__ gsIn, const float* __restrict__ gs2In,
    const float* __restrict__ bng, const float* __restrict__ bnb,
    float* __restrict__ C, float* __restrict__ gs, float* __restrict__ gs2) {
  __shared__ float lsS[NKS * 32], lsH[NKS * 32];
  __shared__ float lred[64];
  int t = threadIdx.x;
  if (BN_A) {
    for (int c = t; c < NKS * 32; c += 256) {
      float sc = 0.f, sh = 0.f;
      if (c < DW) {
        float m = gsIn[c] * (1.f / BATCH);
        float var = gs2In[c] * (1.f / BATCH) - m * m;
        sc = bng[c] * rsqrtf(var + BN_EPS);
        sh = bnb[c] - m * sc;
      }
      lsS[c] = sc; lsH[c] = sh;
    }
  }
  if (t < 64) lred[t] = 0.f;
  __syncthreads();

  int w = t >> 6, lane = t & 63;
  int nl = lane & 15, q = lane >> 4;
  int row = blockIdx.x * 64 + w * 16 + nl;
  int c0 = blockIdx.y * 32;
  f32x4 acc[2];
  acc[0] = (f32x4){0.f, 0.f, 0.f, 0.f};
  acc[1] = (f32x4){0.f, 0.f, 0.f, 0.f};

  short8 araw[2]; f32x4 fraw0[2], fraw1[2]; short8 braw[2][2];
  auto loadA_raw = [&](int ksg, int buf) {
    int kb = ksg * 32 + q * 8;
    if (!BN_A) {
      araw[buf] = *(const short8*)(Abf + (size_t)row * AK + kb);
    } else {
      if (kb + 8 <= KREAL) {
        fraw0[buf] = *(const f32x4*)(Af32 + (size_t)row * KREAL + kb);
        fraw1[buf] = *(const f32x4*)(Af32 + (size_t)row * KREAL + kb + 4);
      } else {
        fraw0[buf] = (f32x4){0.f,0.f,0.f,0.f};
        fraw1[buf] = (f32x4){0.f,0.f,0.f,0.f};
      }
    }
    const u16* wb = wp + (size_t)ksg * (WCOL * 32) + (size_t)(c0 + nl) * 32 + q * 8;
    braw[buf][0] = *(const short8*)wb;
    braw[buf][1] = *(const short8*)(wb + 16 * 32);
  };
  auto cookA = [&](int ksg, int buf) -> short8 {
    if (!BN_A) return araw[buf];
    int kb = ksg * 32 + q * 8;
    f32x4 s0 = *(const f32x4*)&lsS[kb], h0 = *(const f32x4*)&lsH[kb];
    f32x4 s1 = *(const f32x4*)&lsS[kb + 4], h1 = *(const f32x4*)&lsH[kb + 4];
    union { unsigned u[4]; short8 s; } a;
    float v0 = fmaxf(fmaf(fraw0[buf][0], s0[0], h0[0]), 0.f);
    float v1 = fmaxf(fmaf(fraw0[buf][1], s0[1], h0[1]), 0.f);
    float v2 = fmaxf(fmaf(fraw0[buf][2], s0[2], h0[2]), 0.f);
    float v3 = fmaxf(fmaf(fraw0[buf][3], s0[3], h0[3]), 0.f);
    float v4 = fmaxf(fmaf(fraw1[buf][0], s1[0], h1[0]), 0.f);
    float v5 = fmaxf(fmaf(fraw1[buf][1], s1[1], h1[1]), 0.f);
    float v6 = fmaxf(fmaf(fraw1[buf][2], s1[2], h1[2]), 0.f);
    float v7 = fmaxf(fmaf(fraw1[buf][3], s1[3], h1[3]), 0.f);
    a.u[0] = bf16_rne(v0) | (bf16_rne(v1) << 16);
    a.u[1] = bf16_rne(v2) | (bf16_rne(v3) << 16);
    a.u[2] = bf16_rne(v4) | (bf16_rne(v5) << 16);
    a.u[3] = bf16_rne(v6) | (bf16_rne(v7) << 16);
    return a.s;
  };

  loadA_raw(0, 0);
#pragma unroll 4
  for (int ksg = 0; ksg < NKS; ksg++) {
    int cur = ksg & 1;
    if (ksg + 1 < NKS) loadA_raw(ksg + 1, cur ^ 1);
    short8 afr = cookA(ksg, cur);
    acc[0] = __builtin_amdgcn_mfma_f32_16x16x32_bf16(afr, braw[cur][0], acc[0], 0, 0, 0);
    acc[1] = __builtin_amdgcn_mfma_f32_16x16x32_bf16(afr, braw[cur][1], acc[1], 0, 0, 0);
  }

  int rbase = blockIdx.x * 64 + w * 16 + q * 4;
#pragma unroll
  for (int nt = 0; nt < 2; nt++) {
    int col = c0 + nt * 16 + nl;
    if (col < DW) {
      float bi = bias[col];
      float s = 0.f, s2 = 0.f;
#pragma unroll
      for (int r = 0; r < 4; r++) {
        float v = acc[nt][r] + bi;
        C[(size_t)(rbase + r) * DW + col] = v;
        s += v; s2 = fmaf(v, v, s2);
      }
      s += __shfl_xor(s, 16); s2 += __shfl_xor(s2, 16);
      s += __shfl_xor(s, 32); s2 += __shfl_xor(s2, 32);
      if (q == 0) {
        atomicAdd(&lred[nt * 16 + nl], s);
        atomicAdd(&lred[32 + nt * 16 + nl], s2);
      }
    }
  }
  __syncthreads();
  if (t < 32) {
    int col = c0 + t;
    if (col < DW) atomicAdd(&gs[col], lred[t]);
  } else if (t < 64) {
    int col = c0 + t - 32;
    if (col < DW) atomicAdd(&gs2[col], lred[t]);
  }
}

// ---------------------------------------------------------------------------
// Final concat + dot, BN2 finalize folded in-block.
// ---------------------------------------------------------------------------
__global__ __launch_bounds__(256) void k_final(const float* __restrict__ lp,
    const float* __restrict__ res, const float* __restrict__ y2,
    const float* __restrict__ gB, const float* __restrict__ gB2,
    const float* __restrict__ g2, const float* __restrict__ bb2,
    const float* __restrict__ ow, const float* __restrict__ ob,
    float* __restrict__ out) {
  __shared__ float lsS[DW], lsH[DW];
  int t = threadIdx.x;
  for (int c = t; c < DW; c += 256) {
    float m = gB[c] * (1.f / BATCH);
    float var = gB2[c] * (1.f / BATCH) - m * m;
    float sc = g2[c] * rsqrtf(var + BN_EPS);
    lsS[c] = sc;
    lsH[c] = bb2[c] - m * sc;
  }
  __syncthreads();
  int lane = t & 63, w = t >> 6;
  int b = blockIdx.x * 4 + w;
  float acc = 0.f;
  for (int j = lane; j < 593; j += 64) {
    float v;
    if (j == 0)       v = lp[b];
    else if (j < 193) v = res[(size_t)b * 192 + (j - 1)];
    else {
      int c = j - 193;
      v = fmaxf(fmaf(y2[(size_t)b * DW + c], lsS[c], lsH[c]), 0.f);
    }
    acc = fmaf(v, ow[j], acc);
  }
#pragma unroll
  for (int k = 1; k < 64; k <<= 1) acc += __shfl_xor(acc, k);
  if (lane == 0) out[b] = acc + ob[0];
}

// ---------------------------------------------------------------------------
extern "C" void kernel_launch(void* const* d_in, const int* in_sizes, int n_in,
                              void* d_out, int out_size, void* d_ws, size_t ws_size,
                              hipStream_t stream) {
  const int*   feat_index = (const int*)d_in[0];
  const float* emb = (const float*)d_in[2];
  const float* lw  = (const float*)d_in[3];
  const float* lb  = (const float*)d_in[4];
  const float* w1  = (const float*)d_in[5];
  const float* b1  = (const float*)d_in[6];
  const float* w2  = (const float*)d_in[7];
  const float* b2  = (const float*)d_in[8];
  const float* dw1 = (const float*)d_in[9];
  const float* db1 = (const float*)d_in[10];
  const float* g1  = (const float*)d_in[11];
  const float* bb1 = (const float*)d_in[12];
  const float* dw2 = (const float*)d_in[13];
  const float* db2 = (const float*)d_in[14];
  const float* g2  = (const float*)d_in[15];
  const float* bb2 = (const float*)d_in[16];
  const float* ow  = (const float*)d_in[17];
  const float* ob  = (const float*)d_in[18];

  float* ws   = (float*)d_ws;
  u16*  flatb = (u16*)ws;                  // 4096*640 bf16 = 1,310,720 f
  float* y1   = ws + 1310720;              // 4096*400 f32
  float* res  = ws + 2949120;              // 4096*192 f32
  float* lp   = ws + 3735552;              // 4096
  float* gA   = ws + 3741248;              // 400 sum
  float* gA2  = gA + 400;
  float* gB   = gA2 + 400;
  float* gB2  = gB + 400;                  // gstat: 1600 contiguous
  float* y2   = ws + 3742848;              // 4096*400 f32 (nxt removed)
  u16*  wp1   = (u16*)(ws + 5381248);      // 239,616 bf16 = 119,808 f
  u16*  wp2   = (u16*)(ws + 5501056);      // 319,488 bf16 = 159,744 f
  u16*  wpd1  = (u16*)(ws + 5660800);      // 266,240 bf16 = 133,120 f
  u16*  wpd2  = (u16*)(ws + 5793920);      // 173,056 bf16 -> ends 5,880,448 f
  float* out  = (float*)d_out;

  k_gp<<<GATH_B + PREP_B, 256, 0, stream>>>(feat_index, emb, lw, lb, w1, w2,
      dw1, dw2, flatb, lp, wp1, wp2, wpd1, wpd2, gA);
  k_cin_f<<<512, 256, 0, stream>>>(flatb, wp1, wp2, b1, b2, res);
  k_gemm_mfma<false, NKS1, IN_DIM, AK1><<<dim3(BATCH / 64, 13), 256, 0, stream>>>(
      flatb, nullptr, wpd1, db1, nullptr, nullptr, nullptr, nullptr, y1, gA, gA2);
  k_gemm_mfma<true, NKS2, DW, 0><<<dim3(BATCH / 64, 13), 256, 0, stream>>>(
      nullptr, y1, wpd2, db2, gA, gA2, g1, bb1, y2, gB, gB2);
  k_final<<<BATCH / 4, 256, 0, stream>>>(lp, res, y2, gB, gB2, g2, bb2, ow, ob, out);
}